// Round 4
// baseline (4328.845 us; speedup 1.0000x reference)
//
#include <hip/hip_runtime.h>

#define B_    32
#define HW_   3136
#define C_    512
#define H_    128
#define CHK_  49                    // items (chunks) per batch per phase
#define ROWS_ 64                    // rows per item (HW_/CHK_)
#define IPP_  (B_ * CHK_)           // 1568 items per phase
#define TOT_  (2 * IPP_)            // 3136 total items
#define LAG_  98                    // ps items issued before interleave (2 batches)
#define NBLK_ 1024

// Work-queue order: q<LAG_: ps item q. Interleave [LAG_, LAG_+2*(IPP_-LAG_)):
// even -> ps item LAG_+r/2, odd -> out item r/2. Tail: remaining out items.
// => out(b,k) trails ps(b,k) by ~101 items (~40 MB traffic) -> pass-2 L3 hits.

__global__ __launch_bounds__(256, 4) void fused_kernel(
    const float4* __restrict__ c4,
    const float4* __restrict__ w4,
    const float4* __restrict__ h4,
    float4* __restrict__ o4,
    const float* __restrict__ fc1_w,
    const float* __restrict__ fc1_b,
    const float* __restrict__ fc2_w,
    const float* __restrict__ fc2_b,
    unsigned* __restrict__ ctrl,     // [ctr][ps_done[32]][w_ready[32]]
    float* __restrict__ partial,     // [B_][CHK_][C_]
    float* __restrict__ wbuf)        // [B_][3*C_]
{
    __shared__ float s_lds[C_];      // 2 KB; doubles as float4 red[128]
    __shared__ float y_lds[H_];
    __shared__ unsigned q_s;
    __shared__ unsigned last_s;

    unsigned* ctr     = ctrl;
    unsigned* ps_done = ctrl + 1;
    unsigned* w_ready = ctrl + 1 + B_;

    const int t    = threadIdx.x;
    const int col4 = t & 127;
    const int rl   = t >> 7;

    for (;;) {
        if (t == 0)
            q_s = __hip_atomic_fetch_add(ctr, 1u, __ATOMIC_RELAXED, __HIP_MEMORY_SCOPE_AGENT);
        __syncthreads();
        const unsigned q = q_s;
        if (q >= TOT_) return;

        int phase, item;
        if (q < LAG_) { phase = 0; item = (int)q; }
        else if (q < LAG_ + 2 * (IPP_ - LAG_)) {
            const unsigned r = q - LAG_;
            phase = (int)(r & 1u);
            item  = phase ? (int)(r >> 1) : (int)(LAG_ + (r >> 1));
        } else {
            phase = 1;
            item  = (int)(q - (LAG_ + 2 * (IPP_ - LAG_)) + (IPP_ - LAG_));
        }
        const int b = item / CHK_;
        const int k = item - b * CHK_;

        if (phase == 0) {
            // ---------------- partial-sum item: ROWS_ rows of batch b ----------
            long base = ((long)b * HW_ + (long)k * ROWS_ + rl) * (C_ / 4) + col4;
            float4 acc = make_float4(0.f, 0.f, 0.f, 0.f);
            #pragma unroll 4
            for (int r = 0; r < ROWS_ / 2; ++r) {
                const float4 a = c4[base];
                const float4 v = w4[base];
                const float4 u = h4[base];
                acc.x += a.x + v.x + u.x;
                acc.y += a.y + v.y + u.y;
                acc.z += a.z + v.z + u.z;
                acc.w += a.w + v.w + u.w;
                base += 2 * (C_ / 4);
            }
            float4* red = (float4*)s_lds;
            if (rl == 1) red[col4] = acc;
            __syncthreads();
            if (rl == 0) {
                const float4 o = red[col4];
                acc.x += o.x; acc.y += o.y; acc.z += o.z; acc.w += o.w;
                float* pp = partial + ((long)b * CHK_ + k) * C_ + col4 * 4;
                __hip_atomic_store(pp + 0, acc.x, __ATOMIC_RELAXED, __HIP_MEMORY_SCOPE_AGENT);
                __hip_atomic_store(pp + 1, acc.y, __ATOMIC_RELAXED, __HIP_MEMORY_SCOPE_AGENT);
                __hip_atomic_store(pp + 2, acc.z, __ATOMIC_RELAXED, __HIP_MEMORY_SCOPE_AGENT);
                __hip_atomic_store(pp + 3, acc.w, __ATOMIC_RELAXED, __HIP_MEMORY_SCOPE_AGENT);
            }
            __syncthreads();   // drains vmcnt: partial stores complete at coherence point
            if (t == 0) {
                const unsigned old = __hip_atomic_fetch_add(
                    &ps_done[b], 1u, __ATOMIC_ACQ_REL, __HIP_MEMORY_SCOPE_AGENT);
                last_s = (old == CHK_ - 1) ? 1u : 0u;
            }
            __syncthreads();
            if (last_s) {
                // -------- MLP for batch b (runs once, in the finisher block) ----
                for (int c = t; c < C_; c += 256) {
                    float accm = 0.f;
                    const float* p = partial + (long)b * CHK_ * C_ + c;
                    for (int kk = 0; kk < CHK_; ++kk)
                        accm += __hip_atomic_load(p + (long)kk * C_,
                                                  __ATOMIC_RELAXED, __HIP_MEMORY_SCOPE_AGENT);
                    s_lds[c] = accm * (1.0f / (float)HW_);
                }
                __syncthreads();
                if (t < H_) {
                    float accf = fc1_b[t];
                    const float* __restrict__ wr = fc1_w + (long)t * C_;
                    #pragma unroll 4
                    for (int c = 0; c < C_; ++c) accf += s_lds[c] * wr[c];
                    const float x = accf;
                    const float u = 0.7978845608028654f * (x + 0.044715f * x * x * x);
                    y_lds[t] = 0.5f * x * (1.0f + tanhf(u));
                }
                __syncthreads();
                for (int c = t; c < C_; c += 256) {
                    float lg[3];
                    #pragma unroll
                    for (int j = 0; j < 3; ++j) {
                        const int row = j * C_ + c;
                        float a2 = fc2_b[row];
                        const float* __restrict__ wr = fc2_w + (long)row * H_;
                        #pragma unroll 4
                        for (int h = 0; h < H_; ++h) a2 += y_lds[h] * wr[h];
                        lg[j] = a2;
                    }
                    const float m  = fmaxf(lg[0], fmaxf(lg[1], lg[2]));
                    const float e0 = __expf(lg[0] - m);
                    const float e1 = __expf(lg[1] - m);
                    const float e2 = __expf(lg[2] - m);
                    const float inv = 1.0f / (e0 + e1 + e2);
                    float* wb = wbuf + (long)b * 3 * C_;
                    __hip_atomic_store(wb + 0 * C_ + c, e0 * inv, __ATOMIC_RELAXED, __HIP_MEMORY_SCOPE_AGENT);
                    __hip_atomic_store(wb + 1 * C_ + c, e1 * inv, __ATOMIC_RELAXED, __HIP_MEMORY_SCOPE_AGENT);
                    __hip_atomic_store(wb + 2 * C_ + c, e2 * inv, __ATOMIC_RELAXED, __HIP_MEMORY_SCOPE_AGENT);
                }
                __syncthreads();   // drain wbuf stores
                if (t == 0)
                    __hip_atomic_store(&w_ready[b], 1u, __ATOMIC_RELEASE, __HIP_MEMORY_SCOPE_AGENT);
            }
        } else {
            // ---------------- output item: ROWS_ rows of batch b ---------------
            if (t == 0) {
                unsigned spin = 0;
                while (__hip_atomic_load(&w_ready[b], __ATOMIC_ACQUIRE,
                                         __HIP_MEMORY_SCOPE_AGENT) == 0u) {
                    __builtin_amdgcn_s_sleep(16);
                    if (++spin > (1u << 20)) break;   // safety bailout, never expected
                }
            }
            __syncthreads();
            const float* wb = wbuf + (long)b * 3 * C_ + col4 * 4;
            float w0[4], w1[4], w2[4];
            #pragma unroll
            for (int j = 0; j < 4; ++j) {
                w0[j] = __hip_atomic_load(wb + 0 * C_ + j, __ATOMIC_RELAXED, __HIP_MEMORY_SCOPE_AGENT);
                w1[j] = __hip_atomic_load(wb + 1 * C_ + j, __ATOMIC_RELAXED, __HIP_MEMORY_SCOPE_AGENT);
                w2[j] = __hip_atomic_load(wb + 2 * C_ + j, __ATOMIC_RELAXED, __HIP_MEMORY_SCOPE_AGENT);
            }
            long base = ((long)b * HW_ + (long)k * ROWS_ + rl) * (C_ / 4) + col4;
            #pragma unroll 4
            for (int r = 0; r < ROWS_ / 2; ++r) {
                const float4 a = c4[base];
                const float4 v = w4[base];
                const float4 u = h4[base];
                float4 o;
                o.x = a.x * w0[0] + v.x * w1[0] + u.x * w2[0];
                o.y = a.y * w0[1] + v.y * w1[1] + u.y * w2[1];
                o.z = a.z * w0[2] + v.z * w1[2] + u.z * w2[2];
                o.w = a.w * w0[3] + v.w * w1[3] + u.w * w2[3];
                o4[base] = o;
                base += 2 * (C_ / 4);
            }
        }
        __syncthreads();   // protect q_s / LDS reuse across queue iterations
    }
}

// ---------------------------------------------------------------------------
extern "C" void kernel_launch(void* const* d_in, const int* in_sizes, int n_in,
                              void* d_out, int out_size, void* d_ws, size_t ws_size,
                              hipStream_t stream)
{
    const float* c_e   = (const float*)d_in[0];
    const float* w_e   = (const float*)d_in[1];
    const float* h_e   = (const float*)d_in[2];
    const float* fc1_w = (const float*)d_in[3];
    const float* fc1_b = (const float*)d_in[4];
    const float* fc2_w = (const float*)d_in[5];
    const float* fc2_b = (const float*)d_in[6];
    float* out = (float*)d_out;

    // ws layout: [ctrl 512 B][partial B_*CHK_*C_ f32 = 3.21 MB][wbuf B_*3*C_ f32]
    unsigned char* ws = (unsigned char*)d_ws;
    unsigned* ctrl    = (unsigned*)ws;
    float*    partial = (float*)(ws + 512);
    float*    wbuf    = partial + (long)B_ * CHK_ * C_;

    hipMemsetAsync(ctrl, 0, 512, stream);   // zero queue counter + flags (captured)

    fused_kernel<<<NBLK_, 256, 0, stream>>>(
        (const float4*)c_e, (const float4*)w_e, (const float4*)h_e, (float4*)out,
        fc1_w, fc1_b, fc2_w, fc2_b, ctrl, partial, wbuf);
}

// Round 5
// 470.546 us; speedup vs baseline: 9.1996x; 9.1996x over previous
//
#include <hip/hip_runtime.h>

#define B_    32
#define HW_   3136
#define C_    512
#define H_    128
#define CHK_  49                    // items (chunks) per batch per phase
#define ROWS_ 64                    // rows per item (HW_/CHK_)
#define IPP_  (B_ * CHK_)           // 1568 items per phase
#define TOT_  (2 * IPP_)            // 3136 total items
#define LAG_  196                   // ps items issued before interleave (4 batches)
#define NBLK_ 1024

// Queue order: q<LAG_: ps item q. Interleave [LAG_, LAG_+2*(IPP_-LAG_)):
// even -> ps item LAG_+r/2, odd -> out item r/2. Tail: remaining out items.
// out(b,k) trails the last ps item of batch b by ~300 slots (~80 MB traffic)
// -> pass-2 embedding reads are L3 hits (proved in R4: FETCH 611 MB).

__global__ __launch_bounds__(256, 4) void fused_kernel(
    const float4* __restrict__ c4,
    const float4* __restrict__ w4,
    const float4* __restrict__ h4,
    float4* __restrict__ o4,
    const float* __restrict__ fc1_w,
    const float* __restrict__ fc1_b,
    const float* __restrict__ fc2_w,
    const float* __restrict__ fc2_b,
    unsigned* __restrict__ ctrl,     // padded: ctr@[0], ps_done[b]@[64+16b], w_ready[b]@[576+16b]
    float* __restrict__ partial,     // [B_][CHK_][C_]
    float* __restrict__ wbuf)        // [B_][3*C_]
{
    __shared__ float s_lds[C_];      // 2 KB; doubles as float4 red[128]
    __shared__ float y_lds[H_];
    __shared__ unsigned q_s;
    __shared__ unsigned last_s;

    unsigned* ctr = ctrl;

    const int t    = threadIdx.x;
    const int col4 = t & 127;
    const int rl   = t >> 7;

    for (;;) {
        if (t == 0)
            q_s = __hip_atomic_fetch_add(ctr, 1u, __ATOMIC_RELAXED, __HIP_MEMORY_SCOPE_AGENT);
        __syncthreads();
        const unsigned q = q_s;
        __syncthreads();             // all threads read q_s before next overwrite
        if (q >= TOT_) return;

        int phase, item;
        if (q < LAG_) { phase = 0; item = (int)q; }
        else if (q < LAG_ + 2u * (IPP_ - LAG_)) {
            const unsigned r = q - LAG_;
            phase = (int)(r & 1u);
            item  = phase ? (int)(r >> 1) : (int)(LAG_ + (r >> 1));
        } else {
            phase = 1;
            item  = (int)(q - (LAG_ + 2u * (IPP_ - LAG_)) + (IPP_ - LAG_));
        }
        const int b = item / CHK_;
        const int k = item - b * CHK_;

        if (phase == 0) {
            // ---------------- partial-sum item: ROWS_ rows of batch b ----------
            long base = ((long)b * HW_ + (long)k * ROWS_ + rl) * (C_ / 4) + col4;
            float4 acc = make_float4(0.f, 0.f, 0.f, 0.f);
            #pragma unroll 4
            for (int r = 0; r < ROWS_ / 2; ++r) {
                const float4 a = c4[base];
                const float4 v = w4[base];
                const float4 u = h4[base];
                acc.x += a.x + v.x + u.x;
                acc.y += a.y + v.y + u.y;
                acc.z += a.z + v.z + u.z;
                acc.w += a.w + v.w + u.w;
                base += 2 * (C_ / 4);
            }
            float4* red = (float4*)s_lds;
            if (rl == 1) red[col4] = acc;
            __syncthreads();
            if (rl == 0) {
                const float4 o = red[col4];
                acc.x += o.x; acc.y += o.y; acc.z += o.z; acc.w += o.w;
                float* pp = partial + ((long)b * CHK_ + k) * C_ + col4 * 4;
                __hip_atomic_store(pp + 0, acc.x, __ATOMIC_RELAXED, __HIP_MEMORY_SCOPE_AGENT);
                __hip_atomic_store(pp + 1, acc.y, __ATOMIC_RELAXED, __HIP_MEMORY_SCOPE_AGENT);
                __hip_atomic_store(pp + 2, acc.z, __ATOMIC_RELAXED, __HIP_MEMORY_SCOPE_AGENT);
                __hip_atomic_store(pp + 3, acc.w, __ATOMIC_RELAXED, __HIP_MEMORY_SCOPE_AGENT);
            }
            __syncthreads();
            if (t == 0) {
                const unsigned old = __hip_atomic_fetch_add(
                    &ctrl[64 + 16 * b], 1u, __ATOMIC_ACQ_REL, __HIP_MEMORY_SCOPE_AGENT);
                last_s = (old == CHK_ - 1) ? 1u : 0u;
            }
            __syncthreads();
            if (last_s) {
                // -------- MLP for batch b (runs once, in the finisher block) ----
                for (int c = t; c < C_; c += 256) {
                    float accm = 0.f;
                    const float* p = partial + (long)b * CHK_ * C_ + c;
                    for (int kk = 0; kk < CHK_; ++kk)
                        accm += __hip_atomic_load(p + (long)kk * C_,
                                                  __ATOMIC_RELAXED, __HIP_MEMORY_SCOPE_AGENT);
                    s_lds[c] = accm * (1.0f / (float)HW_);
                }
                __syncthreads();
                if (t < H_) {
                    float accf = fc1_b[t];
                    const float* __restrict__ wr = fc1_w + (long)t * C_;
                    #pragma unroll 4
                    for (int c = 0; c < C_; ++c) accf += s_lds[c] * wr[c];
                    const float x = accf;
                    const float u = 0.7978845608028654f * (x + 0.044715f * x * x * x);
                    y_lds[t] = 0.5f * x * (1.0f + tanhf(u));
                }
                __syncthreads();
                for (int c = t; c < C_; c += 256) {
                    float lg[3];
                    #pragma unroll
                    for (int j = 0; j < 3; ++j) {
                        const int row = j * C_ + c;
                        float a2 = fc2_b[row];
                        const float* __restrict__ wr = fc2_w + (long)row * H_;
                        #pragma unroll 4
                        for (int h = 0; h < H_; ++h) a2 += y_lds[h] * wr[h];
                        lg[j] = a2;
                    }
                    const float m  = fmaxf(lg[0], fmaxf(lg[1], lg[2]));
                    const float e0 = __expf(lg[0] - m);
                    const float e1 = __expf(lg[1] - m);
                    const float e2 = __expf(lg[2] - m);
                    const float inv = 1.0f / (e0 + e1 + e2);
                    float* wb = wbuf + (long)b * 3 * C_;
                    __hip_atomic_store(wb + 0 * C_ + c, e0 * inv, __ATOMIC_RELAXED, __HIP_MEMORY_SCOPE_AGENT);
                    __hip_atomic_store(wb + 1 * C_ + c, e1 * inv, __ATOMIC_RELAXED, __HIP_MEMORY_SCOPE_AGENT);
                    __hip_atomic_store(wb + 2 * C_ + c, e2 * inv, __ATOMIC_RELAXED, __HIP_MEMORY_SCOPE_AGENT);
                }
                __syncthreads();
                if (t == 0)
                    __hip_atomic_store(&ctrl[64 + 512 + 16 * b], 1u,
                                       __ATOMIC_RELEASE, __HIP_MEMORY_SCOPE_AGENT);
            }
        } else {
            // ---------------- output item: ROWS_ rows of batch b ---------------
            if (t == 0) {
                // RELAXED poll (no per-iteration cache invalidate!) + sleep.
                unsigned spin = 0;
                while (__hip_atomic_load(&ctrl[64 + 512 + 16 * b], __ATOMIC_RELAXED,
                                         __HIP_MEMORY_SCOPE_AGENT) == 0u) {
                    __builtin_amdgcn_s_sleep(8);
                    if (++spin > (1u << 22)) break;   // safety bailout, never expected
                }
                __builtin_amdgcn_fence(__ATOMIC_ACQUIRE, "agent");  // one inv, not per poll
            }
            __syncthreads();
            const float* wb = wbuf + (long)b * 3 * C_ + col4 * 4;
            float w0[4], w1[4], w2[4];
            #pragma unroll
            for (int j = 0; j < 4; ++j) {
                w0[j] = __hip_atomic_load(wb + 0 * C_ + j, __ATOMIC_RELAXED, __HIP_MEMORY_SCOPE_AGENT);
                w1[j] = __hip_atomic_load(wb + 1 * C_ + j, __ATOMIC_RELAXED, __HIP_MEMORY_SCOPE_AGENT);
                w2[j] = __hip_atomic_load(wb + 2 * C_ + j, __ATOMIC_RELAXED, __HIP_MEMORY_SCOPE_AGENT);
            }
            long base = ((long)b * HW_ + (long)k * ROWS_ + rl) * (C_ / 4) + col4;
            #pragma unroll 4
            for (int r = 0; r < ROWS_ / 2; ++r) {
                const float4 a = c4[base];
                const float4 v = w4[base];
                const float4 u = h4[base];
                float4 o;
                o.x = a.x * w0[0] + v.x * w1[0] + u.x * w2[0];
                o.y = a.y * w0[1] + v.y * w1[1] + u.y * w2[1];
                o.z = a.z * w0[2] + v.z * w1[2] + u.z * w2[2];
                o.w = a.w * w0[3] + v.w * w1[3] + u.w * w2[3];
                o4[base] = o;
                base += 2 * (C_ / 4);
            }
        }
        __syncthreads();   // protect LDS reuse across queue iterations
    }
}

// ---------------------------------------------------------------------------
extern "C" void kernel_launch(void* const* d_in, const int* in_sizes, int n_in,
                              void* d_out, int out_size, void* d_ws, size_t ws_size,
                              hipStream_t stream)
{
    const float* c_e   = (const float*)d_in[0];
    const float* w_e   = (const float*)d_in[1];
    const float* h_e   = (const float*)d_in[2];
    const float* fc1_w = (const float*)d_in[3];
    const float* fc1_b = (const float*)d_in[4];
    const float* fc2_w = (const float*)d_in[5];
    const float* fc2_b = (const float*)d_in[6];
    float* out = (float*)d_out;

    // ws layout: [ctrl 4608 B padded][partial B_*CHK_*C_ f32][wbuf B_*3*C_ f32]
    unsigned char* ws = (unsigned char*)d_ws;
    unsigned* ctrl    = (unsigned*)ws;
    float*    partial = (float*)(ws + 4608);
    float*    wbuf    = partial + (long)B_ * CHK_ * C_;

    hipMemsetAsync(ctrl, 0, 4608, stream);   // zero queue counter + flags (captured)

    fused_kernel<<<NBLK_, 256, 0, stream>>>(
        (const float4*)c_e, (const float4*)w_e, (const float4*)h_e, (float4*)out,
        fc1_w, fc1_b, fc2_w, fc2_b, ctrl, partial, wbuf);
}